// Round 6
// baseline (954.827 us; speedup 1.0000x reference)
//
#include <hip/hip_runtime.h>
#include <hip/hip_bf16.h>

// GIN forward, MI355X. Sizes fixed by the reference.
constexpr int N_NODES  = 100000;
constexpr int N_EDGES  = 1280000;
constexpr int HDIM     = 64;
constexpr int N_GRAPHS = 128;
constexpr int N_RES    = 4;
constexpr int CAP      = 64;       // CSR slots per node (P(deg>64) ~ e-60)
constexpr int ZNODE    = N_NODES;  // zero pad row index in padded h buffers

// ---------------- CSR build: XCD-binned single pass ----------------
constexpr int RNG = 8;
constexpr int RSZ = N_NODES / RNG;      // 12500
constexpr int CHUNKS = 128;
constexpr int CSZ = N_EDGES / CHUNKS;   // 10000

__global__ void fill_kernel(const int* __restrict__ ei,
                            int* __restrict__ cnt, int* __restrict__ csr) {
  int b = blockIdx.x;
  int lo = (b & (RNG - 1)) * RSZ;
  int hi = lo + RSZ;
  int base = (b >> 3) * CSZ;
  for (int i = base + threadIdx.x * 4; i < base + CSZ; i += 256 * 4) {
    int4 d4 = *(const int4*)&ei[N_EDGES + i];
    int4 s4 = *(const int4*)&ei[i];
    if (d4.x >= lo && d4.x < hi) { int p = atomicAdd(&cnt[d4.x], 1); csr[d4.x * CAP + (p & (CAP - 1))] = s4.x; }
    if (d4.y >= lo && d4.y < hi) { int p = atomicAdd(&cnt[d4.y], 1); csr[d4.y * CAP + (p & (CAP - 1))] = s4.y; }
    if (d4.z >= lo && d4.z < hi) { int p = atomicAdd(&cnt[d4.z], 1); csr[d4.z * CAP + (p & (CAP - 1))] = s4.z; }
    if (d4.w >= lo && d4.w < hi) { int p = atomicAdd(&cnt[d4.w], 1); csr[d4.w * CAP + (p & (CAP - 1))] = s4.w; }
  }
}

// write ZNODE sentinel into unused slots [deg..16) of each row (incl. row ZNODE)
__global__ void pad_kernel(const int* __restrict__ cnt, int* __restrict__ csr) {
  int n = blockIdx.x * blockDim.x + threadIdx.x;
  if (n > N_NODES) return;
  int d = cnt[n]; d = d < 16 ? d : 16;
  for (int q = d; q < 16; ++q) csr[(size_t)n * CAP + q] = ZNODE;
}

// copy x into padded buffer (rows 0..N_NODES-1), zero pad row N_NODES
__global__ void copy_pad_kernel(const float* __restrict__ x, float* __restrict__ dst) {
  constexpr int TOT = (N_NODES + 1) * HDIM / 4;   // float4 count
  constexpr int XN  = N_NODES * HDIM / 4;
  for (int i = blockIdx.x * blockDim.x + threadIdx.x; i < TOT; i += gridDim.x * blockDim.x) {
    float4 v = (i < XN) ? *(const float4*)&x[i * 4] : make_float4(0.f, 0.f, 0.f, 0.f);
    *(float4*)&dst[i * 4] = v;
  }
}

// goff[g] = lower_bound(batch, g) over sorted batch ids
__global__ void goff_kernel(const int* __restrict__ batch, int* __restrict__ goff) {
  int g = threadIdx.x;
  if (g > N_GRAPHS) return;
  int lo = 0, hi = N_NODES;
  while (lo < hi) {
    int mid = (lo + hi) >> 1;
    if (batch[mid] < g) lo = mid + 1; else hi = mid;
  }
  goff[g] = lo;
}

__device__ __forceinline__ float tanh_fast(float x) {
  float xc = fminf(fmaxf(x, -15.f), 15.f);
  float e = __expf(2.f * xc);
  return __fdividef(e - 1.f, e + 1.f);
}

// ---------------- fused GIN conv: lane = node, zero LDS ----------------
// Each lane owns one node: z[64] in VGPRs. Gather: 16 unconditional neighbor
// rows (empty slots -> ZNODE zero row), rare deg>16 tail loop. Matvecs: W at
// compile-time uniform addresses -> pure s_load feeding the fma scalar port;
// NO LDS ops anywhere (avoids the shared-lgkmcnt SMEM/LDS serialization).
template <bool RESID>
__global__ __launch_bounds__(64)
void conv_kernel(const float* __restrict__ hin, float* __restrict__ hout,
                 const int* __restrict__ cnt, const int* __restrict__ csr,
                 const float* __restrict__ W1, const float* __restrict__ b1,
                 const float* __restrict__ W2, const float* __restrict__ b2,
                 const float* __restrict__ gam, const float* __restrict__ bet,
                 const float* __restrict__ rm, const float* __restrict__ rv) {
  const int n = blockIdx.x * 64 + threadIdx.x;
  const bool valid = n < N_NODES;
  const int nn = valid ? n : ZNODE;

  const int* row = csr + (size_t)nn * CAP;
  int4 r0 = *(const int4*)(row + 0);
  int4 r1 = *(const int4*)(row + 4);
  int4 r2 = *(const int4*)(row + 8);
  int4 r3 = *(const int4*)(row + 12);
  int d = cnt[nn]; d = d > CAP ? CAP : d;
  int idx[16] = {r0.x, r0.y, r0.z, r0.w, r1.x, r1.y, r1.z, r1.w,
                 r2.x, r2.y, r2.z, r2.w, r3.x, r3.y, r3.z, r3.w};

  // z = own row (self term)
  float z[64];
  {
    const float* sp = hin + (size_t)nn * 64;
#pragma unroll
    for (int c = 0; c < 16; ++c) {
      float4 v = *(const float4*)(sp + c * 4);
      z[c * 4 + 0] = v.x; z[c * 4 + 1] = v.y; z[c * 4 + 2] = v.z; z[c * 4 + 3] = v.w;
    }
  }
  // 16 unconditional neighbor rows (ZNODE rows add zero)
#pragma unroll
  for (int q = 0; q < 16; ++q) {
    const float* sp = hin + (size_t)idx[q] * 64;
#pragma unroll
    for (int c = 0; c < 16; ++c) {
      float4 v = *(const float4*)(sp + c * 4);
      z[c * 4 + 0] += v.x; z[c * 4 + 1] += v.y; z[c * 4 + 2] += v.z; z[c * 4 + 3] += v.w;
    }
  }
  // rare tail (deg > 16), per-lane predicated
  for (int q = 16; q < d; ++q) {
    const float* sp = hin + (size_t)row[q] * 64;
#pragma unroll
    for (int c = 0; c < 16; ++c) {
      float4 v = *(const float4*)(sp + c * 4);
      z[c * 4 + 0] += v.x; z[c * 4 + 1] += v.y; z[c * 4 + 2] += v.z; z[c * 4 + 3] += v.w;
    }
  }

  // ---- matvec 1: a1 = relu(z @ W1 + b1) ----
  float a1[64];
#pragma unroll
  for (int c = 0; c < 4; ++c) {
    float acc[16];
#pragma unroll
    for (int f = 0; f < 16; ++f) acc[f] = b1[c * 16 + f];
#pragma unroll
    for (int k = 0; k < 64; ++k) {
#pragma unroll
      for (int f = 0; f < 16; ++f)
        acc[f] = fmaf(z[k], W1[k * 64 + c * 16 + f], acc[f]);   // uniform -> s_load
    }
#pragma unroll
    for (int f = 0; f < 16; ++f) a1[c * 16 + f] = fmaxf(acc[f], 0.0f);
  }

  // ---- matvec 2 + ReLU + BN (+residual) + store, chunk-wise ----
#pragma unroll
  for (int c = 0; c < 4; ++c) {
    float acc[16];
#pragma unroll
    for (int f = 0; f < 16; ++f) acc[f] = b2[c * 16 + f];
#pragma unroll
    for (int k = 0; k < 64; ++k) {
#pragma unroll
      for (int f = 0; f < 16; ++f)
        acc[f] = fmaf(a1[k], W2[k * 64 + c * 16 + f], acc[f]);
    }
    if (valid) {
      float y[16];
#pragma unroll
      for (int f = 0; f < 16; ++f) {
        float sc = gam[c * 16 + f] * rsqrtf(rv[c * 16 + f] + 1e-5f);
        float sh = bet[c * 16 + f] - rm[c * 16 + f] * sc;
        y[f] = fmaxf(acc[f], 0.0f) * sc + sh;
      }
      if (RESID) {
#pragma unroll
        for (int cc = 0; cc < 4; ++cc) {
          float4 r = *(const float4*)&hin[(size_t)n * 64 + c * 16 + cc * 4];
          y[cc * 4 + 0] += r.x; y[cc * 4 + 1] += r.y;
          y[cc * 4 + 2] += r.z; y[cc * 4 + 3] += r.w;
        }
      }
#pragma unroll
      for (int cc = 0; cc < 4; ++cc) {
        float4 s = make_float4(y[cc * 4 + 0], y[cc * 4 + 1], y[cc * 4 + 2], y[cc * 4 + 3]);
        *(float4*)&hout[(size_t)n * 64 + c * 16 + cc * 4] = s;
      }
    }
  }
}

// ---------------- head: tanh(h @ W + b), lane = node, zero LDS ----------------
__global__ __launch_bounds__(64)
void head_kernel(const float* __restrict__ hin, float* __restrict__ hb,
                 const float* __restrict__ W, const float* __restrict__ b) {
  const int n = blockIdx.x * 64 + threadIdx.x;
  const bool valid = n < N_NODES;
  const int nn = valid ? n : ZNODE;

  float z[64];
  {
    const float* sp = hin + (size_t)nn * 64;
#pragma unroll
    for (int c = 0; c < 16; ++c) {
      float4 v = *(const float4*)(sp + c * 4);
      z[c * 4 + 0] = v.x; z[c * 4 + 1] = v.y; z[c * 4 + 2] = v.z; z[c * 4 + 3] = v.w;
    }
  }

#pragma unroll
  for (int c = 0; c < 4; ++c) {
    float acc[16];
#pragma unroll
    for (int f = 0; f < 16; ++f) acc[f] = b[c * 16 + f];
#pragma unroll
    for (int k = 0; k < 64; ++k) {
#pragma unroll
      for (int f = 0; f < 16; ++f)
        acc[f] = fmaf(z[k], W[k * 64 + c * 16 + f], acc[f]);
    }
    if (valid) {
#pragma unroll
      for (int cc = 0; cc < 4; ++cc) {
        float4 s = make_float4(tanh_fast(acc[cc * 4 + 0]), tanh_fast(acc[cc * 4 + 1]),
                               tanh_fast(acc[cc * 4 + 2]), tanh_fast(acc[cc * 4 + 3]));
        *(float4*)&hb[(size_t)n * 64 + c * 16 + cc * 4] = s;
      }
    }
  }
}

// ---------------- per-graph mean pool (batch is sorted) ----------------
__global__ void pool_kernel(const float* __restrict__ hb, const int* __restrict__ goff,
                            float* __restrict__ out) {
  __shared__ float red[4][64];
  int g = blockIdx.x;
  int s = goff[g], e = goff[g + 1];
  int j = threadIdx.x & 63, w = threadIdx.x >> 6;
  float acc = 0.0f;
  for (int r = s + w; r < e; r += 4) acc += hb[(size_t)r * 64 + j];
  red[w][j] = acc;
  __syncthreads();
  if (w == 0) {
    float tt = red[0][j] + red[1][j] + red[2][j] + red[3][j];
    out[g * 64 + j] = tt / fmaxf((float)(e - s), 1.0f);
  }
}

// ---------------- launch ----------------
extern "C" void kernel_launch(void* const* d_in, const int* in_sizes, int n_in,
                              void* d_out, int out_size, void* d_ws, size_t ws_size,
                              hipStream_t stream) {
  const float* x     = (const float*)d_in[0];
  const int*   ei    = (const int*)d_in[1];
  const int*   batch = (const int*)d_in[2];
  const float* c1_W1 = (const float*)d_in[3];
  const float* c1_b1 = (const float*)d_in[4];
  const float* c1_W2 = (const float*)d_in[5];
  const float* c1_b2 = (const float*)d_in[6];
  const float* c1_g  = (const float*)d_in[7];
  const float* c1_be = (const float*)d_in[8];
  const float* c1_m  = (const float*)d_in[9];
  const float* c1_v  = (const float*)d_in[10];
  const float* cs_W1 = (const float*)d_in[11];
  const float* cs_b1 = (const float*)d_in[12];
  const float* cs_W2 = (const float*)d_in[13];
  const float* cs_b2 = (const float*)d_in[14];
  const float* cs_g  = (const float*)d_in[15];
  const float* cs_be = (const float*)d_in[16];
  const float* cs_m  = (const float*)d_in[17];
  const float* cs_v  = (const float*)d_in[18];
  const float* lin_W = (const float*)d_in[19];
  const float* lin_b = (const float*)d_in[20];
  float* out = (float*)d_out;

  size_t cur = 0;
  auto take = [&](size_t bytes) -> void* {
    void* p = (char*)d_ws + cur;
    cur += (bytes + 255) & ~(size_t)255;
    return p;
  };
  int* cnt  = (int*)take((N_NODES + 1) * sizeof(int));
  size_t zbytes = cur;                       // cnt zeroed every call
  int* goff = (int*)take((N_GRAPHS + 1) * sizeof(int));
  int* csr  = (int*)take((size_t)(N_NODES + 1) * CAP * sizeof(int));
  float* bufA = (float*)take((size_t)(N_NODES + 1) * HDIM * sizeof(float));
  float* bufB = (float*)take((size_t)(N_NODES + 1) * HDIM * sizeof(float));
  (void)ws_size; (void)in_sizes; (void)n_in; (void)out_size;

  hipMemsetAsync(cnt, 0, zbytes, stream);
  hipMemsetAsync(bufA + (size_t)ZNODE * HDIM, 0, HDIM * sizeof(float), stream);

  fill_kernel<<<RNG * CHUNKS, 256, 0, stream>>>(ei, cnt, csr);
  pad_kernel<<<(N_NODES + 256) / 256, 256, 0, stream>>>(cnt, csr);
  copy_pad_kernel<<<2048, 256, 0, stream>>>(x, bufB);   // x -> padded bufB
  goff_kernel<<<1, 256, 0, stream>>>(batch, goff);

  const int NBLK = (N_NODES + 63) / 64;      // 1563, 1 wave per block

  // conv1: bufB -> bufA
  conv_kernel<false><<<NBLK, 64, 0, stream>>>(bufB, bufA, cnt, csr,
      c1_W1, c1_b1, c1_W2, c1_b2, c1_g, c1_be, c1_m, c1_v);

  // 4 residual convs: A->B->A->B->A
  float* srcp = bufA;
  float* dstp = bufB;
  for (int l = 0; l < N_RES; ++l) {
    conv_kernel<true><<<NBLK, 64, 0, stream>>>(srcp, dstp, cnt, csr,
        cs_W1 + l * 4096, cs_b1 + l * 64, cs_W2 + l * 4096, cs_b2 + l * 64,
        cs_g + l * 64, cs_be + l * 64, cs_m + l * 64, cs_v + l * 64);
    float* tmp = srcp; srcp = dstp; dstp = tmp;
  }
  // final h in bufA (srcp); head: bufA -> bufB
  head_kernel<<<NBLK, 64, 0, stream>>>(srcp, dstp, lin_W, lin_b);
  pool_kernel<<<N_GRAPHS, 256, 0, stream>>>(dstp, goff, out);
}

// Round 7
// 734.695 us; speedup vs baseline: 1.2996x; 1.2996x over previous
//
#include <hip/hip_runtime.h>
#include <hip/hip_bf16.h>

// GIN forward, MI355X. Sizes fixed by the reference.
constexpr int N_NODES  = 100000;
constexpr int N_EDGES  = 1280000;
constexpr int HDIM     = 64;
constexpr int N_GRAPHS = 128;
constexpr int N_RES    = 4;
constexpr int CAP      = 64;       // CSR slots per node (P(deg>64) ~ e-60)
constexpr int ZNODE    = N_NODES;  // zero pad row index in padded h buffers

// ---- bf16 helpers (RNE) ----
__device__ __forceinline__ unsigned f2bf1(float f) {
  unsigned u = __float_as_uint(f);
  return (u + 0x7fffu + ((u >> 16) & 1u)) >> 16;
}
__device__ __forceinline__ unsigned packbf(float lo, float hi) {
  return f2bf1(lo) | (f2bf1(hi) << 16);
}
__device__ __forceinline__ float bflo(unsigned u) { return __uint_as_float(u << 16); }
__device__ __forceinline__ float bfhi(unsigned u) { return __uint_as_float(u & 0xffff0000u); }

__device__ __forceinline__ float tanh_fast(float x) {
  float xc = fminf(fmaxf(x, -15.f), 15.f);
  float e = __expf(2.f * xc);
  return __fdividef(e - 1.f, e + 1.f);
}

// ---------------- CSR build: XCD-binned single pass ----------------
// range (b&7) == XCD id under round-robin: all writes to a node row funnel
// through one XCD's L2 (range CSR = 3.2MB < 4MB) -> write coalescing in L2.
constexpr int RNG = 8;
constexpr int RSZ = N_NODES / RNG;      // 12500
constexpr int CHUNKS = 128;
constexpr int CSZ = N_EDGES / CHUNKS;   // 10000

__global__ void fill_kernel(const int* __restrict__ ei,
                            int* __restrict__ cnt, int* __restrict__ csr) {
  int b = blockIdx.x;
  int lo = (b & (RNG - 1)) * RSZ;
  int hi = lo + RSZ;
  int base = (b >> 3) * CSZ;
  for (int i = base + threadIdx.x * 4; i < base + CSZ; i += 256 * 4) {
    int4 d4 = *(const int4*)&ei[N_EDGES + i];
    int4 s4 = *(const int4*)&ei[i];
    if (d4.x >= lo && d4.x < hi) { int p = atomicAdd(&cnt[d4.x], 1); csr[d4.x * CAP + (p & (CAP - 1))] = s4.x; }
    if (d4.y >= lo && d4.y < hi) { int p = atomicAdd(&cnt[d4.y], 1); csr[d4.y * CAP + (p & (CAP - 1))] = s4.y; }
    if (d4.z >= lo && d4.z < hi) { int p = atomicAdd(&cnt[d4.z], 1); csr[d4.z * CAP + (p & (CAP - 1))] = s4.z; }
    if (d4.w >= lo && d4.w < hi) { int p = atomicAdd(&cnt[d4.w], 1); csr[d4.w * CAP + (p & (CAP - 1))] = s4.w; }
  }
}

// write ZNODE sentinel into unused slots [deg..16) of each row (incl. row ZNODE)
__global__ void pad_kernel(const int* __restrict__ cnt, int* __restrict__ csr) {
  int n = blockIdx.x * blockDim.x + threadIdx.x;
  if (n > N_NODES) return;
  int d = cnt[n]; d = d < 16 ? d : 16;
  for (int q = d; q < 16; ++q) csr[(size_t)n * CAP + q] = ZNODE;
}

// x (f32) -> padded bf16 buffer; pad row zero
__global__ void cvt_pad_kernel(const float* __restrict__ x, unsigned short* __restrict__ dst) {
  constexpr int TOT = (N_NODES + 1) * HDIM / 2;   // uint (bf16x2) count
  constexpr int XN  = N_NODES * HDIM / 2;
  unsigned* d = (unsigned*)dst;
  for (int i = blockIdx.x * blockDim.x + threadIdx.x; i < TOT; i += gridDim.x * blockDim.x) {
    unsigned v = 0;
    if (i < XN) { float2 f = *(const float2*)&x[i * 2]; v = packbf(f.x, f.y); }
    d[i] = v;
  }
}

// goff[g] = lower_bound(batch, g) over sorted batch ids
__global__ void goff_kernel(const int* __restrict__ batch, int* __restrict__ goff) {
  int g = threadIdx.x;
  if (g > N_GRAPHS) return;
  int lo = 0, hi = N_NODES;
  while (lo < hi) {
    int mid = (lo + hi) >> 1;
    if (batch[mid] < g) lo = mid + 1; else hi = mid;
  }
  goff[g] = lo;
}

// ---------------- fused GIN conv ----------------
// 64-thr (1 wave) block = 64 nodes. Gather: node PAIR per pass, half-wave per
// node, lane = 2 features (uint = bf16x2) -> each load instr reads two whole
// 128B rows coalesced. CSR slots are block-uniform -> s_load. z transposed
// via 9.2KB LDS (packed bf16x2). Matvec: z[64] in VGPR, W at kernel-arg +
// literal offsets -> pure s_load (R6-proven fast path), zero LDS ops.
template <bool RESID>
__global__ __launch_bounds__(64)
void conv_kernel(const unsigned short* __restrict__ hin, unsigned short* __restrict__ hout,
                 const int* __restrict__ cnt, const int* __restrict__ csr,
                 const float* __restrict__ W1, const float* __restrict__ b1,
                 const float* __restrict__ W2, const float* __restrict__ b2,
                 const float* __restrict__ gam, const float* __restrict__ bet,
                 const float* __restrict__ rm, const float* __restrict__ rv) {
  __shared__ unsigned zbuf[64][36];      // [node][featpair], pad 36
  const int ln = threadIdx.x;
  const int lc = ln & 31;
  const bool hiH = ln >= 32;
  const int nb = blockIdx.x * 64;
  const unsigned* hb = (const unsigned*)hin;   // row stride 32 words

  for (int p = 0; p < 32; ++p) {
    int nA = nb + 2 * p; if (nA > ZNODE) nA = ZNODE;
    int nB = nA + 1;     if (nB > ZNODE) nB = ZNODE;
    const int* rA = csr + (size_t)nA * CAP;
    const int* rB = csr + (size_t)nB * CAP;
    int4 a0 = *(const int4*)(rA + 0), a1q = *(const int4*)(rA + 4);
    int4 a2 = *(const int4*)(rA + 8), a3q = *(const int4*)(rA + 12);
    int4 b0 = *(const int4*)(rB + 0), b1q = *(const int4*)(rB + 4);
    int4 b2q = *(const int4*)(rB + 8), b3q = *(const int4*)(rB + 12);
    int dA = cnt[nA], dB = cnt[nB];

    int self = hiH ? nB : nA;
    float z0, z1;
    { unsigned u = hb[(size_t)self * 32 + lc]; z0 = bflo(u); z1 = bfhi(u); }
    int i0  = hiH ? b0.x  : a0.x;   int i1  = hiH ? b0.y  : a0.y;
    int i2  = hiH ? b0.z  : a0.z;   int i3  = hiH ? b0.w  : a0.w;
    int i4  = hiH ? b1q.x : a1q.x;  int i5  = hiH ? b1q.y : a1q.y;
    int i6  = hiH ? b1q.z : a1q.z;  int i7  = hiH ? b1q.w : a1q.w;
    int i8  = hiH ? b2q.x : a2.x;   int i9  = hiH ? b2q.y : a2.y;
    int i10 = hiH ? b2q.z : a2.z;   int i11 = hiH ? b2q.w : a2.w;
    int i12 = hiH ? b3q.x : a3q.x;  int i13 = hiH ? b3q.y : a3q.y;
    int i14 = hiH ? b3q.z : a3q.z;  int i15 = hiH ? b3q.w : a3q.w;
#define GACC(ix) { unsigned u = hb[(size_t)(ix) * 32 + lc]; z0 += bflo(u); z1 += bfhi(u); }
    GACC(i0)  GACC(i1)  GACC(i2)  GACC(i3)
    GACC(i4)  GACC(i5)  GACC(i6)  GACC(i7)
    GACC(i8)  GACC(i9)  GACC(i10) GACC(i11)
    GACC(i12) GACC(i13) GACC(i14) GACC(i15)
#undef GACC
    if (dA > 16 && !hiH)
      for (int q = 16; q < dA; ++q) { unsigned u = hb[(size_t)rA[q] * 32 + lc]; z0 += bflo(u); z1 += bfhi(u); }
    if (dB > 16 && hiH)
      for (int q = 16; q < dB; ++q) { unsigned u = hb[(size_t)rB[q] * 32 + lc]; z0 += bflo(u); z1 += bfhi(u); }
    zbuf[2 * p + (hiH ? 1 : 0)][lc] = packbf(z0, z1);
  }
  __syncthreads();

  // ---- z[64] into registers (lane = node ln) ----
  float z[64];
#pragma unroll
  for (int cc = 0; cc < 8; ++cc) {
    uint4 u = *(const uint4*)&zbuf[ln][cc * 4];
    z[cc * 8 + 0] = bflo(u.x); z[cc * 8 + 1] = bfhi(u.x);
    z[cc * 8 + 2] = bflo(u.y); z[cc * 8 + 3] = bfhi(u.y);
    z[cc * 8 + 4] = bflo(u.z); z[cc * 8 + 5] = bfhi(u.z);
    z[cc * 8 + 6] = bflo(u.w); z[cc * 8 + 7] = bfhi(u.w);
  }

  // ---- matvec 1: a1 = relu(z @ W1 + b1); literal W offsets -> s_load ----
  float a1v[64];
#pragma unroll
  for (int c = 0; c < 4; ++c) {
    float acc[16];
#pragma unroll
    for (int f = 0; f < 16; ++f) acc[f] = b1[c * 16 + f];
#pragma unroll
    for (int k = 0; k < 64; ++k) {
#pragma unroll
      for (int f = 0; f < 16; ++f)
        acc[f] = fmaf(z[k], W1[k * 64 + c * 16 + f], acc[f]);
    }
#pragma unroll
    for (int f = 0; f < 16; ++f) a1v[c * 16 + f] = fmaxf(acc[f], 0.0f);
  }

  // ---- matvec 2 + ReLU + BN (+residual) + bf16 store ----
  const int n = nb + ln;
  const bool valid = n < N_NODES;
  unsigned* ho = (unsigned*)hout;
#pragma unroll
  for (int c = 0; c < 4; ++c) {
    float acc[16];
#pragma unroll
    for (int f = 0; f < 16; ++f) acc[f] = b2[c * 16 + f];
#pragma unroll
    for (int k = 0; k < 64; ++k) {
#pragma unroll
      for (int f = 0; f < 16; ++f)
        acc[f] = fmaf(a1v[k], W2[k * 64 + c * 16 + f], acc[f]);
    }
    if (valid) {
      float y[16];
#pragma unroll
      for (int f = 0; f < 16; ++f) {
        float sc = gam[c * 16 + f] * rsqrtf(rv[c * 16 + f] + 1e-5f);
        float sh = bet[c * 16 + f] - rm[c * 16 + f] * sc;
        y[f] = fmaxf(acc[f], 0.0f) * sc + sh;
      }
      if (RESID) {
        uint4 r0 = *(const uint4*)&hb[(size_t)n * 32 + c * 8];
        uint4 r1 = *(const uint4*)&hb[(size_t)n * 32 + c * 8 + 4];
        y[0]  += bflo(r0.x); y[1]  += bfhi(r0.x);
        y[2]  += bflo(r0.y); y[3]  += bfhi(r0.y);
        y[4]  += bflo(r0.z); y[5]  += bfhi(r0.z);
        y[6]  += bflo(r0.w); y[7]  += bfhi(r0.w);
        y[8]  += bflo(r1.x); y[9]  += bfhi(r1.x);
        y[10] += bflo(r1.y); y[11] += bfhi(r1.y);
        y[12] += bflo(r1.z); y[13] += bfhi(r1.z);
        y[14] += bflo(r1.w); y[15] += bfhi(r1.w);
      }
      uint4 s0, s1;
      s0.x = packbf(y[0],  y[1]);  s0.y = packbf(y[2],  y[3]);
      s0.z = packbf(y[4],  y[5]);  s0.w = packbf(y[6],  y[7]);
      s1.x = packbf(y[8],  y[9]);  s1.y = packbf(y[10], y[11]);
      s1.z = packbf(y[12], y[13]); s1.w = packbf(y[14], y[15]);
      *(uint4*)&ho[(size_t)n * 32 + c * 8]     = s0;
      *(uint4*)&ho[(size_t)n * 32 + c * 8 + 4] = s1;
    }
  }
}

// ---------------- head: tanh(h @ W + b); bf16 in, f32 out ----------------
__global__ __launch_bounds__(64)
void head_kernel(const unsigned short* __restrict__ hin, float* __restrict__ hb,
                 const float* __restrict__ W, const float* __restrict__ b) {
  const int ln = threadIdx.x;
  const int n = blockIdx.x * 64 + ln;
  const bool valid = n < N_NODES;
  const int nn = valid ? n : ZNODE;
  const unsigned* hbw = (const unsigned*)hin;

  float z[64];
#pragma unroll
  for (int cc = 0; cc < 8; ++cc) {
    uint4 u = *(const uint4*)&hbw[(size_t)nn * 32 + cc * 4];
    z[cc * 8 + 0] = bflo(u.x); z[cc * 8 + 1] = bfhi(u.x);
    z[cc * 8 + 2] = bflo(u.y); z[cc * 8 + 3] = bfhi(u.y);
    z[cc * 8 + 4] = bflo(u.z); z[cc * 8 + 5] = bfhi(u.z);
    z[cc * 8 + 6] = bflo(u.w); z[cc * 8 + 7] = bfhi(u.w);
  }

#pragma unroll
  for (int c = 0; c < 4; ++c) {
    float acc[16];
#pragma unroll
    for (int f = 0; f < 16; ++f) acc[f] = b[c * 16 + f];
#pragma unroll
    for (int k = 0; k < 64; ++k) {
#pragma unroll
      for (int f = 0; f < 16; ++f)
        acc[f] = fmaf(z[k], W[k * 64 + c * 16 + f], acc[f]);
    }
    if (valid) {
#pragma unroll
      for (int cc = 0; cc < 4; ++cc) {
        float4 s = make_float4(tanh_fast(acc[cc * 4 + 0]), tanh_fast(acc[cc * 4 + 1]),
                               tanh_fast(acc[cc * 4 + 2]), tanh_fast(acc[cc * 4 + 3]));
        *(float4*)&hb[(size_t)n * 64 + c * 16 + cc * 4] = s;
      }
    }
  }
}

// ---------------- per-graph mean pool (batch is sorted) ----------------
__global__ void pool_kernel(const float* __restrict__ hb, const int* __restrict__ goff,
                            float* __restrict__ out) {
  __shared__ float red[4][64];
  int g = blockIdx.x;
  int s = goff[g], e = goff[g + 1];
  int j = threadIdx.x & 63, w = threadIdx.x >> 6;
  float acc = 0.0f;
  for (int r = s + w; r < e; r += 4) acc += hb[(size_t)r * 64 + j];
  red[w][j] = acc;
  __syncthreads();
  if (w == 0) {
    float tt = red[0][j] + red[1][j] + red[2][j] + red[3][j];
    out[g * 64 + j] = tt / fmaxf((float)(e - s), 1.0f);
  }
}

// ---------------- launch ----------------
extern "C" void kernel_launch(void* const* d_in, const int* in_sizes, int n_in,
                              void* d_out, int out_size, void* d_ws, size_t ws_size,
                              hipStream_t stream) {
  const float* x     = (const float*)d_in[0];
  const int*   ei    = (const int*)d_in[1];
  const int*   batch = (const int*)d_in[2];
  const float* c1_W1 = (const float*)d_in[3];
  const float* c1_b1 = (const float*)d_in[4];
  const float* c1_W2 = (const float*)d_in[5];
  const float* c1_b2 = (const float*)d_in[6];
  const float* c1_g  = (const float*)d_in[7];
  const float* c1_be = (const float*)d_in[8];
  const float* c1_m  = (const float*)d_in[9];
  const float* c1_v  = (const float*)d_in[10];
  const float* cs_W1 = (const float*)d_in[11];
  const float* cs_b1 = (const float*)d_in[12];
  const float* cs_W2 = (const float*)d_in[13];
  const float* cs_b2 = (const float*)d_in[14];
  const float* cs_g  = (const float*)d_in[15];
  const float* cs_be = (const float*)d_in[16];
  const float* cs_m  = (const float*)d_in[17];
  const float* cs_v  = (const float*)d_in[18];
  const float* lin_W = (const float*)d_in[19];
  const float* lin_b = (const float*)d_in[20];
  float* out = (float*)d_out;

  size_t cur = 0;
  auto take = [&](size_t bytes) -> void* {
    void* p = (char*)d_ws + cur;
    cur += (bytes + 255) & ~(size_t)255;
    return p;
  };
  int* cnt  = (int*)take((N_NODES + 1) * sizeof(int));
  size_t zbytes = cur;                       // cnt zeroed every call
  int* goff = (int*)take((N_GRAPHS + 1) * sizeof(int));
  int* csr  = (int*)take((size_t)(N_NODES + 1) * CAP * sizeof(int));
  unsigned short* bufA = (unsigned short*)take((size_t)(N_NODES + 1) * HDIM * sizeof(unsigned short));
  unsigned short* bufB = (unsigned short*)take((size_t)(N_NODES + 1) * HDIM * sizeof(unsigned short));
  float* hbF = (float*)take((size_t)N_NODES * HDIM * sizeof(float));
  (void)ws_size; (void)in_sizes; (void)n_in; (void)out_size;

  hipMemsetAsync(cnt, 0, zbytes, stream);
  hipMemsetAsync(bufA + (size_t)ZNODE * HDIM, 0, HDIM * sizeof(unsigned short), stream);

  fill_kernel<<<RNG * CHUNKS, 256, 0, stream>>>(ei, cnt, csr);
  pad_kernel<<<(N_NODES + 256) / 256, 256, 0, stream>>>(cnt, csr);
  cvt_pad_kernel<<<2048, 256, 0, stream>>>(x, bufB);   // x -> padded bf16 bufB
  goff_kernel<<<1, 256, 0, stream>>>(batch, goff);

  const int NBLK = (N_NODES + 63) / 64;      // 1563, 1 wave per block

  // conv1: bufB(x) -> bufA
  conv_kernel<false><<<NBLK, 64, 0, stream>>>(bufB, bufA, cnt, csr,
      c1_W1, c1_b1, c1_W2, c1_b2, c1_g, c1_be, c1_m, c1_v);

  // 4 residual convs: A->B->A->B->A
  unsigned short* srcp = bufA;
  unsigned short* dstp = bufB;
  for (int l = 0; l < N_RES; ++l) {
    conv_kernel<true><<<NBLK, 64, 0, stream>>>(srcp, dstp, cnt, csr,
        cs_W1 + l * 4096, cs_b1 + l * 64, cs_W2 + l * 4096, cs_b2 + l * 64,
        cs_g + l * 64, cs_be + l * 64, cs_m + l * 64, cs_v + l * 64);
    unsigned short* tmp = srcp; srcp = dstp; dstp = tmp;
  }
  // final h in bufA (srcp); head: bufA -> hbF (f32)
  head_kernel<<<NBLK, 64, 0, stream>>>(srcp, hbF, lin_W, lin_b);
  pool_kernel<<<N_GRAPHS, 256, 0, stream>>>(hbF, goff, out);
}

// Round 8
// 483.667 us; speedup vs baseline: 1.9741x; 1.5190x over previous
//
#include <hip/hip_runtime.h>
#include <hip/hip_bf16.h>

// GIN forward, MI355X. Sizes fixed by the reference.
constexpr int N_NODES  = 100000;
constexpr int N_EDGES  = 1280000;
constexpr int HDIM     = 64;
constexpr int N_GRAPHS = 128;
constexpr int N_RES    = 4;
constexpr int CAP      = 64;       // CSR slots per node (P(deg>64) ~ e-60)
constexpr int ZNODE    = N_NODES;  // zero pad row index in padded h buffers

// ---- bf16 helpers (RNE) ----
__device__ __forceinline__ unsigned f2bf1(float f) {
  unsigned u = __float_as_uint(f);
  return (u + 0x7fffu + ((u >> 16) & 1u)) >> 16;
}
__device__ __forceinline__ unsigned packbf(float lo, float hi) {
  return f2bf1(lo) | (f2bf1(hi) << 16);
}
__device__ __forceinline__ float bflo(unsigned u) { return __uint_as_float(u << 16); }
__device__ __forceinline__ float bfhi(unsigned u) { return __uint_as_float(u & 0xffff0000u); }

__device__ __forceinline__ float tanh_fast(float x) {
  float xc = fminf(fmaxf(x, -15.f), 15.f);
  float e = __expf(2.f * xc);
  return __fdividef(e - 1.f, e + 1.f);
}

// ---------------- CSR build: XCD-binned single pass ----------------
constexpr int RNG = 8;
constexpr int RSZ = N_NODES / RNG;      // 12500
constexpr int CHUNKS = 128;
constexpr int CSZ = N_EDGES / CHUNKS;   // 10000

__global__ void fill_kernel(const int* __restrict__ ei,
                            int* __restrict__ cnt, int* __restrict__ csr) {
  int b = blockIdx.x;
  int lo = (b & (RNG - 1)) * RSZ;
  int hi = lo + RSZ;
  int base = (b >> 3) * CSZ;
  for (int i = base + threadIdx.x * 4; i < base + CSZ; i += 256 * 4) {
    int4 d4 = *(const int4*)&ei[N_EDGES + i];
    int4 s4 = *(const int4*)&ei[i];
    if (d4.x >= lo && d4.x < hi) { int p = atomicAdd(&cnt[d4.x], 1); csr[d4.x * CAP + (p & (CAP - 1))] = s4.x; }
    if (d4.y >= lo && d4.y < hi) { int p = atomicAdd(&cnt[d4.y], 1); csr[d4.y * CAP + (p & (CAP - 1))] = s4.y; }
    if (d4.z >= lo && d4.z < hi) { int p = atomicAdd(&cnt[d4.z], 1); csr[d4.z * CAP + (p & (CAP - 1))] = s4.z; }
    if (d4.w >= lo && d4.w < hi) { int p = atomicAdd(&cnt[d4.w], 1); csr[d4.w * CAP + (p & (CAP - 1))] = s4.w; }
  }
}

// write ZNODE sentinel into unused slots [deg..16) of each row (incl. row ZNODE)
__global__ void pad_kernel(const int* __restrict__ cnt, int* __restrict__ csr) {
  int n = blockIdx.x * blockDim.x + threadIdx.x;
  if (n > N_NODES) return;
  int d = cnt[n]; d = d < 16 ? d : 16;
  for (int q = d; q < 16; ++q) csr[(size_t)n * CAP + q] = ZNODE;
}

// x (f32) -> padded bf16 buffer; pad row zero
__global__ void cvt_pad_kernel(const float* __restrict__ x, unsigned short* __restrict__ dst) {
  constexpr int TOT = (N_NODES + 1) * HDIM / 2;   // uint (bf16x2) count
  constexpr int XN  = N_NODES * HDIM / 2;
  unsigned* d = (unsigned*)dst;
  for (int i = blockIdx.x * blockDim.x + threadIdx.x; i < TOT; i += gridDim.x * blockDim.x) {
    unsigned v = 0;
    if (i < XN) { float2 f = *(const float2*)&x[i * 2]; v = packbf(f.x, f.y); }
    d[i] = v;
  }
}

// goff[g] = lower_bound(batch, g) over sorted batch ids
__global__ void goff_kernel(const int* __restrict__ batch, int* __restrict__ goff) {
  int g = threadIdx.x;
  if (g > N_GRAPHS) return;
  int lo = 0, hi = N_NODES;
  while (lo < hi) {
    int mid = (lo + hi) >> 1;
    if (batch[mid] < g) lo = mid + 1; else hi = mid;
  }
  goff[g] = lo;
}

// ---------------- fused GIN conv: 256 thr = 4 waves, 64 nodes ----------------
// Gather: wave w gathers its 16 nodes (8 pair-passes, half-wave per node,
// lane = 2 features bf16x2, whole-row coalesced loads, CSR slots s_load'ed,
// ZNODE sentinel = branch-free) -> zbuf f32 [64][65] (all LDS ops <=2-way).
// Matvec: lane = node, wave w computes features [16w,16w+16). z/a1 burst-
// loaded from LDS to regs OUTSIDE fma loops (32 at a time); W/b/BN via
// kernel-arg + literal offsets -> pure s_load scalar operands (R7-proven).
template <bool RESID>
__global__ __launch_bounds__(256, 6)
void conv_kernel(const unsigned short* __restrict__ hin, unsigned short* __restrict__ hout,
                 const int* __restrict__ cnt, const int* __restrict__ csr,
                 const float* __restrict__ W1, const float* __restrict__ b1,
                 const float* __restrict__ W2, const float* __restrict__ b2,
                 const float* __restrict__ gam, const float* __restrict__ bet,
                 const float* __restrict__ rm, const float* __restrict__ rv) {
  __shared__ float zbuf[64][65];
  const int t   = threadIdx.x;
  const int ln  = t & 63;
  const int wid = __builtin_amdgcn_readfirstlane(t >> 6);
  const int lc  = ln & 31;
  const bool hiH = ln >= 32;
  const int nb  = blockIdx.x * 64;
  const unsigned* hb = (const unsigned*)hin;   // row stride 32 words

  // ---- gather: wave wid -> local nodes [16*wid, 16*wid+16), 8 pairs ----
  for (int p = 0; p < 8; ++p) {
    int m = wid * 16 + 2 * p;
    int nA = nb + m; if (nA > ZNODE) nA = ZNODE;
    int nB = nA + 1; if (nB > ZNODE) nB = ZNODE;
    const int* rA = csr + (size_t)nA * CAP;
    const int* rB = csr + (size_t)nB * CAP;
    int4 a0 = *(const int4*)(rA + 0), a1q = *(const int4*)(rA + 4);
    int4 a2 = *(const int4*)(rA + 8), a3q = *(const int4*)(rA + 12);
    int4 b0 = *(const int4*)(rB + 0), b1q = *(const int4*)(rB + 4);
    int4 b2q = *(const int4*)(rB + 8), b3q = *(const int4*)(rB + 12);
    int dA = cnt[nA], dB = cnt[nB];

    int self = hiH ? nB : nA;
    float z0, z1;
    { unsigned u = hb[(size_t)self * 32 + lc]; z0 = bflo(u); z1 = bfhi(u); }
    int i0  = hiH ? b0.x  : a0.x;   int i1  = hiH ? b0.y  : a0.y;
    int i2  = hiH ? b0.z  : a0.z;   int i3  = hiH ? b0.w  : a0.w;
    int i4  = hiH ? b1q.x : a1q.x;  int i5  = hiH ? b1q.y : a1q.y;
    int i6  = hiH ? b1q.z : a1q.z;  int i7  = hiH ? b1q.w : a1q.w;
    int i8  = hiH ? b2q.x : a2.x;   int i9  = hiH ? b2q.y : a2.y;
    int i10 = hiH ? b2q.z : a2.z;   int i11 = hiH ? b2q.w : a2.w;
    int i12 = hiH ? b3q.x : a3q.x;  int i13 = hiH ? b3q.y : a3q.y;
    int i14 = hiH ? b3q.z : a3q.z;  int i15 = hiH ? b3q.w : a3q.w;
#define GACC(ix) { unsigned u = hb[(size_t)(ix) * 32 + lc]; z0 += bflo(u); z1 += bfhi(u); }
    GACC(i0)  GACC(i1)  GACC(i2)  GACC(i3)
    GACC(i4)  GACC(i5)  GACC(i6)  GACC(i7)
    GACC(i8)  GACC(i9)  GACC(i10) GACC(i11)
    GACC(i12) GACC(i13) GACC(i14) GACC(i15)
#undef GACC
    if (dA > 16 && !hiH)
      for (int q = 16; q < dA; ++q) { unsigned u = hb[(size_t)rA[q] * 32 + lc]; z0 += bflo(u); z1 += bfhi(u); }
    if (dB > 16 && hiH)
      for (int q = 16; q < dB; ++q) { unsigned u = hb[(size_t)rB[q] * 32 + lc]; z0 += bflo(u); z1 += bfhi(u); }
    int mr = m + (hiH ? 1 : 0);
    zbuf[mr][2 * lc]     = z0;
    zbuf[mr][2 * lc + 1] = z1;
  }
  __syncthreads();

  const float* W1p = W1 + wid * 16;
  const float* W2p = W2 + wid * 16;
  const float* b1p = b1 + wid * 16;
  const float* b2p = b2 + wid * 16;

  // ---- matvec 1: features [16w,16w+16) of relu(z @ W1 + b1), node = ln ----
  float acc[16];
#pragma unroll
  for (int f = 0; f < 16; ++f) acc[f] = b1p[f];
  {
    float zr[32];
#pragma unroll
    for (int w = 0; w < 32; ++w) zr[w] = zbuf[ln][w];
#pragma unroll
    for (int w = 0; w < 32; ++w)
#pragma unroll
      for (int f = 0; f < 16; ++f) acc[f] = fmaf(zr[w], W1p[w * 64 + f], acc[f]);
#pragma unroll
    for (int w = 0; w < 32; ++w) zr[w] = zbuf[ln][32 + w];
#pragma unroll
    for (int w = 0; w < 32; ++w)
#pragma unroll
      for (int f = 0; f < 16; ++f) acc[f] = fmaf(zr[w], W1p[(32 + w) * 64 + f], acc[f]);
  }
  __syncthreads();                      // all z reads complete
#pragma unroll
  for (int f = 0; f < 16; ++f) zbuf[ln][wid * 16 + f] = fmaxf(acc[f], 0.0f);
  __syncthreads();                      // a1 fully written

  // ---- matvec 2: a1 @ W2 + b2 ----
#pragma unroll
  for (int f = 0; f < 16; ++f) acc[f] = b2p[f];
  {
    float ar[32];
#pragma unroll
    for (int w = 0; w < 32; ++w) ar[w] = zbuf[ln][w];
#pragma unroll
    for (int w = 0; w < 32; ++w)
#pragma unroll
      for (int f = 0; f < 16; ++f) acc[f] = fmaf(ar[w], W2p[w * 64 + f], acc[f]);
#pragma unroll
    for (int w = 0; w < 32; ++w) ar[w] = zbuf[ln][32 + w];
#pragma unroll
    for (int w = 0; w < 32; ++w)
#pragma unroll
      for (int f = 0; f < 16; ++f) acc[f] = fmaf(ar[w], W2p[(32 + w) * 64 + f], acc[f]);
  }

  // ---- ReLU + BN (+residual) + bf16 store of feature chunk ----
  const int n = nb + ln;
  if (n < N_NODES) {
    const float* gp = gam + wid * 16;
    const float* bp = bet + wid * 16;
    const float* mp = rm  + wid * 16;
    const float* vp = rv  + wid * 16;
    float y[16];
#pragma unroll
    for (int f = 0; f < 16; ++f) {
      float sc = gp[f] * rsqrtf(vp[f] + 1e-5f);
      float sh = bp[f] - mp[f] * sc;
      y[f] = fmaxf(acc[f], 0.0f) * sc + sh;
    }
    if (RESID) {
      uint4 r0 = *(const uint4*)&hb[(size_t)n * 32 + wid * 8];
      uint4 r1 = *(const uint4*)&hb[(size_t)n * 32 + wid * 8 + 4];
      y[0]  += bflo(r0.x); y[1]  += bfhi(r0.x);
      y[2]  += bflo(r0.y); y[3]  += bfhi(r0.y);
      y[4]  += bflo(r0.z); y[5]  += bfhi(r0.z);
      y[6]  += bflo(r0.w); y[7]  += bfhi(r0.w);
      y[8]  += bflo(r1.x); y[9]  += bfhi(r1.x);
      y[10] += bflo(r1.y); y[11] += bfhi(r1.y);
      y[12] += bflo(r1.z); y[13] += bfhi(r1.z);
      y[14] += bflo(r1.w); y[15] += bfhi(r1.w);
    }
    unsigned* ho = (unsigned*)hout;
    uint4 s0, s1;
    s0.x = packbf(y[0],  y[1]);  s0.y = packbf(y[2],  y[3]);
    s0.z = packbf(y[4],  y[5]);  s0.w = packbf(y[6],  y[7]);
    s1.x = packbf(y[8],  y[9]);  s1.y = packbf(y[10], y[11]);
    s1.z = packbf(y[12], y[13]); s1.w = packbf(y[14], y[15]);
    *(uint4*)&ho[(size_t)n * 32 + wid * 8]     = s0;
    *(uint4*)&ho[(size_t)n * 32 + wid * 8 + 4] = s1;
  }
}

// ---------------- head: tanh(h @ W + b); feature-split, no LDS ----------------
__global__ __launch_bounds__(256, 6)
void head_kernel(const unsigned short* __restrict__ hin, float* __restrict__ hbF,
                 const float* __restrict__ W, const float* __restrict__ b) {
  const int t   = threadIdx.x;
  const int ln  = t & 63;
  const int wid = __builtin_amdgcn_readfirstlane(t >> 6);
  const int n = blockIdx.x * 64 + ln;
  const int nn = (n < N_NODES) ? n : ZNODE;
  const unsigned* hb = (const unsigned*)hin;

  unsigned zp[32];
#pragma unroll
  for (int cc = 0; cc < 8; ++cc) {
    uint4 u = *(const uint4*)&hb[(size_t)nn * 32 + cc * 4];
    zp[cc * 4 + 0] = u.x; zp[cc * 4 + 1] = u.y;
    zp[cc * 4 + 2] = u.z; zp[cc * 4 + 3] = u.w;
  }

  const float* Wp = W + wid * 16;
  const float* bp = b + wid * 16;
  float acc[16];
#pragma unroll
  for (int f = 0; f < 16; ++f) acc[f] = bp[f];
#pragma unroll
  for (int w = 0; w < 32; ++w) {
    float zlo = bflo(zp[w]), zhi = bfhi(zp[w]);
#pragma unroll
    for (int f = 0; f < 16; ++f) acc[f] = fmaf(zlo, Wp[(2 * w) * 64 + f], acc[f]);
#pragma unroll
    for (int f = 0; f < 16; ++f) acc[f] = fmaf(zhi, Wp[(2 * w + 1) * 64 + f], acc[f]);
  }

  if (n < N_NODES) {
#pragma unroll
    for (int cc = 0; cc < 4; ++cc) {
      float4 s = make_float4(tanh_fast(acc[cc * 4 + 0]), tanh_fast(acc[cc * 4 + 1]),
                             tanh_fast(acc[cc * 4 + 2]), tanh_fast(acc[cc * 4 + 3]));
      *(float4*)&hbF[(size_t)n * 64 + wid * 16 + cc * 4] = s;
    }
  }
}

// ---------------- per-graph mean pool (batch is sorted) ----------------
__global__ void pool_kernel(const float* __restrict__ hb, const int* __restrict__ goff,
                            float* __restrict__ out) {
  __shared__ float red[4][64];
  int g = blockIdx.x;
  int s = goff[g], e = goff[g + 1];
  int j = threadIdx.x & 63, w = threadIdx.x >> 6;
  float acc = 0.0f;
  for (int r = s + w; r < e; r += 4) acc += hb[(size_t)r * 64 + j];
  red[w][j] = acc;
  __syncthreads();
  if (w == 0) {
    float tt = red[0][j] + red[1][j] + red[2][j] + red[3][j];
    out[g * 64 + j] = tt / fmaxf((float)(e - s), 1.0f);
  }
}

// ---------------- launch ----------------
extern "C" void kernel_launch(void* const* d_in, const int* in_sizes, int n_in,
                              void* d_out, int out_size, void* d_ws, size_t ws_size,
                              hipStream_t stream) {
  const float* x     = (const float*)d_in[0];
  const int*   ei    = (const int*)d_in[1];
  const int*   batch = (const int*)d_in[2];
  const float* c1_W1 = (const float*)d_in[3];
  const float* c1_b1 = (const float*)d_in[4];
  const float* c1_W2 = (const float*)d_in[5];
  const float* c1_b2 = (const float*)d_in[6];
  const float* c1_g  = (const float*)d_in[7];
  const float* c1_be = (const float*)d_in[8];
  const float* c1_m  = (const float*)d_in[9];
  const float* c1_v  = (const float*)d_in[10];
  const float* cs_W1 = (const float*)d_in[11];
  const float* cs_b1 = (const float*)d_in[12];
  const float* cs_W2 = (const float*)d_in[13];
  const float* cs_b2 = (const float*)d_in[14];
  const float* cs_g  = (const float*)d_in[15];
  const float* cs_be = (const float*)d_in[16];
  const float* cs_m  = (const float*)d_in[17];
  const float* cs_v  = (const float*)d_in[18];
  const float* lin_W = (const float*)d_in[19];
  const float* lin_b = (const float*)d_in[20];
  float* out = (float*)d_out;

  size_t cur = 0;
  auto take = [&](size_t bytes) -> void* {
    void* p = (char*)d_ws + cur;
    cur += (bytes + 255) & ~(size_t)255;
    return p;
  };
  int* cnt  = (int*)take((N_NODES + 1) * sizeof(int));
  size_t zbytes = cur;                       // cnt zeroed every call
  int* goff = (int*)take((N_GRAPHS + 1) * sizeof(int));
  int* csr  = (int*)take((size_t)(N_NODES + 1) * CAP * sizeof(int));
  unsigned short* bufA = (unsigned short*)take((size_t)(N_NODES + 1) * HDIM * sizeof(unsigned short));
  unsigned short* bufB = (unsigned short*)take((size_t)(N_NODES + 1) * HDIM * sizeof(unsigned short));
  float* hbF = (float*)take((size_t)N_NODES * HDIM * sizeof(float));
  (void)ws_size; (void)in_sizes; (void)n_in; (void)out_size;

  hipMemsetAsync(cnt, 0, zbytes, stream);
  hipMemsetAsync(bufA + (size_t)ZNODE * HDIM, 0, HDIM * sizeof(unsigned short), stream);

  fill_kernel<<<RNG * CHUNKS, 256, 0, stream>>>(ei, cnt, csr);
  pad_kernel<<<(N_NODES + 256) / 256, 256, 0, stream>>>(cnt, csr);
  cvt_pad_kernel<<<2048, 256, 0, stream>>>(x, bufB);   // x -> padded bf16 bufB
  goff_kernel<<<1, 256, 0, stream>>>(batch, goff);

  const int NBLK = (N_NODES + 63) / 64;      // 1563 blocks x 256 thr (4 waves)

  // conv1: bufB(x) -> bufA
  conv_kernel<false><<<NBLK, 256, 0, stream>>>(bufB, bufA, cnt, csr,
      c1_W1, c1_b1, c1_W2, c1_b2, c1_g, c1_be, c1_m, c1_v);

  // 4 residual convs: A->B->A->B->A
  unsigned short* srcp = bufA;
  unsigned short* dstp = bufB;
  for (int l = 0; l < N_RES; ++l) {
    conv_kernel<true><<<NBLK, 256, 0, stream>>>(srcp, dstp, cnt, csr,
        cs_W1 + l * 4096, cs_b1 + l * 64, cs_W2 + l * 4096, cs_b2 + l * 64,
        cs_g + l * 64, cs_be + l * 64, cs_m + l * 64, cs_v + l * 64);
    unsigned short* tmp = srcp; srcp = dstp; dstp = tmp;
  }
  // final h in bufA (srcp); head: bufA -> hbF (f32)
  head_kernel<<<NBLK, 256, 0, stream>>>(srcp, hbF, lin_W, lin_b);
  pool_kernel<<<N_GRAPHS, 256, 0, stream>>>(hbF, goff, out);
}

// Round 9
// 456.522 us; speedup vs baseline: 2.0915x; 1.0595x over previous
//
#include <hip/hip_runtime.h>
#include <hip/hip_bf16.h>

// GIN forward, MI355X. Sizes fixed by the reference.
constexpr int N_NODES  = 100000;
constexpr int N_EDGES  = 1280000;
constexpr int HDIM     = 64;
constexpr int N_GRAPHS = 128;
constexpr int N_RES    = 4;
constexpr int CAP      = 64;       // CSR slots per node (P(deg>64) ~ e-60)
constexpr int ZNODE    = N_NODES;  // zero pad row index in padded h buffers

// ---- bf16 helpers (RNE) ----
__device__ __forceinline__ unsigned f2bf1(float f) {
  unsigned u = __float_as_uint(f);
  return (u + 0x7fffu + ((u >> 16) & 1u)) >> 16;
}
__device__ __forceinline__ unsigned packbf(float lo, float hi) {
  return f2bf1(lo) | (f2bf1(hi) << 16);
}
__device__ __forceinline__ float bflo(unsigned u) { return __uint_as_float(u << 16); }
__device__ __forceinline__ float bfhi(unsigned u) { return __uint_as_float(u & 0xffff0000u); }

__device__ __forceinline__ float tanh_fast(float x) {
  float xc = fminf(fmaxf(x, -15.f), 15.f);
  float e = __expf(2.f * xc);
  return __fdividef(e - 1.f, e + 1.f);
}

// ---------------- CSR build: XCD-binned single pass ----------------
constexpr int RNG = 8;
constexpr int RSZ = N_NODES / RNG;      // 12500
constexpr int CHUNKS = 128;
constexpr int CSZ = N_EDGES / CHUNKS;   // 10000

__global__ void fill_kernel(const int* __restrict__ ei,
                            int* __restrict__ cnt, int* __restrict__ csr) {
  int b = blockIdx.x;
  int lo = (b & (RNG - 1)) * RSZ;
  int hi = lo + RSZ;
  int base = (b >> 3) * CSZ;
  for (int i = base + threadIdx.x * 4; i < base + CSZ; i += 256 * 4) {
    int4 d4 = *(const int4*)&ei[N_EDGES + i];
    int4 s4 = *(const int4*)&ei[i];
    if (d4.x >= lo && d4.x < hi) { int p = atomicAdd(&cnt[d4.x], 1); csr[d4.x * CAP + (p & (CAP - 1))] = s4.x; }
    if (d4.y >= lo && d4.y < hi) { int p = atomicAdd(&cnt[d4.y], 1); csr[d4.y * CAP + (p & (CAP - 1))] = s4.y; }
    if (d4.z >= lo && d4.z < hi) { int p = atomicAdd(&cnt[d4.z], 1); csr[d4.z * CAP + (p & (CAP - 1))] = s4.z; }
    if (d4.w >= lo && d4.w < hi) { int p = atomicAdd(&cnt[d4.w], 1); csr[d4.w * CAP + (p & (CAP - 1))] = s4.w; }
  }
}

// pre-write ZNODE sentinel into slots 0..15 of every row (runs BEFORE fill;
// fill overwrites slots < deg). Replaces the old dependent pad pass.
__global__ void prefill_kernel(int* __restrict__ csr) {
  int n = blockIdx.x * blockDim.x + threadIdx.x;
  if (n > N_NODES) return;
  int4 z4 = make_int4(ZNODE, ZNODE, ZNODE, ZNODE);
  int4* p = (int4*)(csr + (size_t)n * CAP);
  p[0] = z4; p[1] = z4; p[2] = z4; p[3] = z4;
}

// x (f32) -> padded bf16 buffer; pad row zero
__global__ void cvt_pad_kernel(const float* __restrict__ x, unsigned short* __restrict__ dst) {
  constexpr int TOT = (N_NODES + 1) * HDIM / 2;   // uint (bf16x2) count
  constexpr int XN  = N_NODES * HDIM / 2;
  unsigned* d = (unsigned*)dst;
  for (int i = blockIdx.x * blockDim.x + threadIdx.x; i < TOT; i += gridDim.x * blockDim.x) {
    unsigned v = 0;
    if (i < XN) { float2 f = *(const float2*)&x[i * 2]; v = packbf(f.x, f.y); }
    d[i] = v;
  }
}

// goff[g] = lower_bound(batch, g) over sorted batch ids
__global__ void goff_kernel(const int* __restrict__ batch, int* __restrict__ goff) {
  int g = threadIdx.x;
  if (g > N_GRAPHS) return;
  int lo = 0, hi = N_NODES;
  while (lo < hi) {
    int mid = (lo + hi) >> 1;
    if (batch[mid] < g) lo = mid + 1; else hi = mid;
  }
  goff[g] = lo;
}

// ---------------- fused GIN conv: 512 thr = 8 waves, 64 nodes ----------------
// Gather: wave w gathers nodes [8w,8w+8) (4 pair-passes, half-wave per node,
// lane = 2 features bf16x2, whole-row coalesced loads, CSR slots s_load'ed,
// ZNODE sentinel = branch-free) -> zbuf f32 [64][65] (all LDS ops <=2-way).
// Matvec: lane = node, wave w computes features [8w,8w+8). z/a1 burst-loaded
// from LDS to regs outside the fma loops; W/b/BN via kernel-arg + literal
// offsets -> pure s_load scalar operands (R8-proven).
template <bool RESID>
__global__ __launch_bounds__(512, 6)
void conv_kernel(const unsigned short* __restrict__ hin, unsigned short* __restrict__ hout,
                 const int* __restrict__ cnt, const int* __restrict__ csr,
                 const float* __restrict__ W1, const float* __restrict__ b1,
                 const float* __restrict__ W2, const float* __restrict__ b2,
                 const float* __restrict__ gam, const float* __restrict__ bet,
                 const float* __restrict__ rm, const float* __restrict__ rv) {
  __shared__ float zbuf[64][65];
  const int t   = threadIdx.x;
  const int ln  = t & 63;
  const int wid = __builtin_amdgcn_readfirstlane(t >> 6);   // 0..7
  const int lc  = ln & 31;
  const bool hiH = ln >= 32;
  const int nb  = blockIdx.x * 64;
  const unsigned* hb = (const unsigned*)hin;   // row stride 32 words

  // ---- gather: wave wid -> local nodes [8*wid, 8*wid+8), 4 pairs ----
  for (int p = 0; p < 4; ++p) {
    int m = wid * 8 + 2 * p;
    int nA = nb + m; if (nA > ZNODE) nA = ZNODE;
    int nB = nA + 1; if (nB > ZNODE) nB = ZNODE;
    const int* rA = csr + (size_t)nA * CAP;
    const int* rB = csr + (size_t)nB * CAP;
    int4 a0 = *(const int4*)(rA + 0), a1q = *(const int4*)(rA + 4);
    int4 a2 = *(const int4*)(rA + 8), a3q = *(const int4*)(rA + 12);
    int4 b0 = *(const int4*)(rB + 0), b1q = *(const int4*)(rB + 4);
    int4 b2q = *(const int4*)(rB + 8), b3q = *(const int4*)(rB + 12);
    int dA = cnt[nA], dB = cnt[nB];

    int self = hiH ? nB : nA;
    float z0, z1;
    { unsigned u = hb[(size_t)self * 32 + lc]; z0 = bflo(u); z1 = bfhi(u); }
    int i0  = hiH ? b0.x  : a0.x;   int i1  = hiH ? b0.y  : a0.y;
    int i2  = hiH ? b0.z  : a0.z;   int i3  = hiH ? b0.w  : a0.w;
    int i4  = hiH ? b1q.x : a1q.x;  int i5  = hiH ? b1q.y : a1q.y;
    int i6  = hiH ? b1q.z : a1q.z;  int i7  = hiH ? b1q.w : a1q.w;
    int i8  = hiH ? b2q.x : a2.x;   int i9  = hiH ? b2q.y : a2.y;
    int i10 = hiH ? b2q.z : a2.z;   int i11 = hiH ? b2q.w : a2.w;
    int i12 = hiH ? b3q.x : a3q.x;  int i13 = hiH ? b3q.y : a3q.y;
    int i14 = hiH ? b3q.z : a3q.z;  int i15 = hiH ? b3q.w : a3q.w;
#define GACC(ix) { unsigned u = hb[(size_t)(ix) * 32 + lc]; z0 += bflo(u); z1 += bfhi(u); }
    GACC(i0)  GACC(i1)  GACC(i2)  GACC(i3)
    GACC(i4)  GACC(i5)  GACC(i6)  GACC(i7)
    GACC(i8)  GACC(i9)  GACC(i10) GACC(i11)
    GACC(i12) GACC(i13) GACC(i14) GACC(i15)
#undef GACC
    if (dA > 16 && !hiH)
      for (int q = 16; q < dA; ++q) { unsigned u = hb[(size_t)rA[q] * 32 + lc]; z0 += bflo(u); z1 += bfhi(u); }
    if (dB > 16 && hiH)
      for (int q = 16; q < dB; ++q) { unsigned u = hb[(size_t)rB[q] * 32 + lc]; z0 += bflo(u); z1 += bfhi(u); }
    int mr = m + (hiH ? 1 : 0);
    zbuf[mr][2 * lc]     = z0;
    zbuf[mr][2 * lc + 1] = z1;
  }
  __syncthreads();

  const float* W1p = W1 + wid * 8;
  const float* W2p = W2 + wid * 8;
  const float* b1p = b1 + wid * 8;
  const float* b2p = b2 + wid * 8;

  // ---- matvec 1: features [8w,8w+8) of relu(z @ W1 + b1), node = ln ----
  float acc[8];
#pragma unroll
  for (int f = 0; f < 8; ++f) acc[f] = b1p[f];
  {
    float zr[32];
#pragma unroll
    for (int w = 0; w < 32; ++w) zr[w] = zbuf[ln][w];
#pragma unroll
    for (int w = 0; w < 32; ++w)
#pragma unroll
      for (int f = 0; f < 8; ++f) acc[f] = fmaf(zr[w], W1p[w * 64 + f], acc[f]);
#pragma unroll
    for (int w = 0; w < 32; ++w) zr[w] = zbuf[ln][32 + w];
#pragma unroll
    for (int w = 0; w < 32; ++w)
#pragma unroll
      for (int f = 0; f < 8; ++f) acc[f] = fmaf(zr[w], W1p[(32 + w) * 64 + f], acc[f]);
  }
  __syncthreads();                      // all z reads complete
#pragma unroll
  for (int f = 0; f < 8; ++f) zbuf[ln][wid * 8 + f] = fmaxf(acc[f], 0.0f);
  __syncthreads();                      // a1 fully written

  // ---- matvec 2: a1 @ W2 + b2 ----
#pragma unroll
  for (int f = 0; f < 8; ++f) acc[f] = b2p[f];
  {
    float ar[32];
#pragma unroll
    for (int w = 0; w < 32; ++w) ar[w] = zbuf[ln][w];
#pragma unroll
    for (int w = 0; w < 32; ++w)
#pragma unroll
      for (int f = 0; f < 8; ++f) acc[f] = fmaf(ar[w], W2p[w * 64 + f], acc[f]);
#pragma unroll
    for (int w = 0; w < 32; ++w) ar[w] = zbuf[ln][32 + w];
#pragma unroll
    for (int w = 0; w < 32; ++w)
#pragma unroll
      for (int f = 0; f < 8; ++f) acc[f] = fmaf(ar[w], W2p[(32 + w) * 64 + f], acc[f]);
  }

  // ---- ReLU + BN (+residual) + bf16 store of 8-feature chunk ----
  const int n = nb + ln;
  if (n < N_NODES) {
    const float* gp = gam + wid * 8;
    const float* bp = bet + wid * 8;
    const float* mp = rm  + wid * 8;
    const float* vp = rv  + wid * 8;
    float y[8];
#pragma unroll
    for (int f = 0; f < 8; ++f) {
      float sc = gp[f] * rsqrtf(vp[f] + 1e-5f);
      float sh = bp[f] - mp[f] * sc;
      y[f] = fmaxf(acc[f], 0.0f) * sc + sh;
    }
    if (RESID) {
      uint4 r0 = *(const uint4*)&hb[(size_t)n * 32 + wid * 4];
      y[0] += bflo(r0.x); y[1] += bfhi(r0.x);
      y[2] += bflo(r0.y); y[3] += bfhi(r0.y);
      y[4] += bflo(r0.z); y[5] += bfhi(r0.z);
      y[6] += bflo(r0.w); y[7] += bfhi(r0.w);
    }
    unsigned* ho = (unsigned*)hout;
    uint4 s0;
    s0.x = packbf(y[0], y[1]); s0.y = packbf(y[2], y[3]);
    s0.z = packbf(y[4], y[5]); s0.w = packbf(y[6], y[7]);
    *(uint4*)&ho[(size_t)n * 32 + wid * 4] = s0;
  }
}

// ---------------- fused head + mean-pool partial sums ----------------
// lane = node, wave w computes features [8w,8w+8): tanh(h @ W + b), then
// per-graph masked 64-lane butterfly sum + atomicAdd into out (zeroed at
// launch). batch is sorted, so a 64-node block spans ~1-2 graphs.
__global__ __launch_bounds__(512, 6)
void head_pool_kernel(const unsigned short* __restrict__ hin, float* __restrict__ out,
                      const int* __restrict__ batch,
                      const float* __restrict__ W, const float* __restrict__ b) {
  const int t   = threadIdx.x;
  const int ln  = t & 63;
  const int wid = __builtin_amdgcn_readfirstlane(t >> 6);
  const int n = blockIdx.x * 64 + ln;
  const bool valid = n < N_NODES;
  const int nn = valid ? n : ZNODE;
  const unsigned* hb = (const unsigned*)hin;

  unsigned zp[32];
#pragma unroll
  for (int cc = 0; cc < 8; ++cc) {
    uint4 u = *(const uint4*)&hb[(size_t)nn * 32 + cc * 4];
    zp[cc * 4 + 0] = u.x; zp[cc * 4 + 1] = u.y;
    zp[cc * 4 + 2] = u.z; zp[cc * 4 + 3] = u.w;
  }

  const float* Wp = W + wid * 8;
  const float* bp = b + wid * 8;
  float acc[8];
#pragma unroll
  for (int f = 0; f < 8; ++f) acc[f] = bp[f];
#pragma unroll
  for (int w = 0; w < 32; ++w) {
    float zlo = bflo(zp[w]), zhi = bfhi(zp[w]);
#pragma unroll
    for (int f = 0; f < 8; ++f) acc[f] = fmaf(zlo, Wp[(2 * w) * 64 + f], acc[f]);
#pragma unroll
    for (int f = 0; f < 8; ++f) acc[f] = fmaf(zhi, Wp[(2 * w + 1) * 64 + f], acc[f]);
  }
#pragma unroll
  for (int f = 0; f < 8; ++f) acc[f] = tanh_fast(acc[f]);

  // per-graph segmented reduction over the block's 64 nodes
  int bg = valid ? batch[n] : -1;
  int gmax = bg;
#pragma unroll
  for (int off = 32; off >= 1; off >>= 1) gmax = max(gmax, __shfl_xor(gmax, off));
  gmax = __builtin_amdgcn_readfirstlane(gmax);
  int g0 = __builtin_amdgcn_readfirstlane(bg);   // lane 0 valid always

  for (int g = g0; g <= gmax; ++g) {
    float s[8];
    bool inG = (bg == g);
#pragma unroll
    for (int f = 0; f < 8; ++f) s[f] = inG ? acc[f] : 0.0f;
#pragma unroll
    for (int off = 1; off <= 32; off <<= 1) {
#pragma unroll
      for (int f = 0; f < 8; ++f) s[f] += __shfl_xor(s[f], off);
    }
    float sv = s[0];
    sv = (ln == 1) ? s[1] : sv;  sv = (ln == 2) ? s[2] : sv;
    sv = (ln == 3) ? s[3] : sv;  sv = (ln == 4) ? s[4] : sv;
    sv = (ln == 5) ? s[5] : sv;  sv = (ln == 6) ? s[6] : sv;
    sv = (ln == 7) ? s[7] : sv;
    if (ln < 8) atomicAdd(&out[g * 64 + wid * 8 + ln], sv);
  }
}

// out[g][f] /= max(count_g, 1)
__global__ void div_kernel(float* __restrict__ out, const int* __restrict__ goff) {
  int i = blockIdx.x * blockDim.x + threadIdx.x;
  if (i >= N_GRAPHS * 64) return;
  int g = i >> 6;
  int c = goff[g + 1] - goff[g];
  out[i] /= (float)max(c, 1);
}

// ---------------- launch ----------------
extern "C" void kernel_launch(void* const* d_in, const int* in_sizes, int n_in,
                              void* d_out, int out_size, void* d_ws, size_t ws_size,
                              hipStream_t stream) {
  const float* x     = (const float*)d_in[0];
  const int*   ei    = (const int*)d_in[1];
  const int*   batch = (const int*)d_in[2];
  const float* c1_W1 = (const float*)d_in[3];
  const float* c1_b1 = (const float*)d_in[4];
  const float* c1_W2 = (const float*)d_in[5];
  const float* c1_b2 = (const float*)d_in[6];
  const float* c1_g  = (const float*)d_in[7];
  const float* c1_be = (const float*)d_in[8];
  const float* c1_m  = (const float*)d_in[9];
  const float* c1_v  = (const float*)d_in[10];
  const float* cs_W1 = (const float*)d_in[11];
  const float* cs_b1 = (const float*)d_in[12];
  const float* cs_W2 = (const float*)d_in[13];
  const float* cs_b2 = (const float*)d_in[14];
  const float* cs_g  = (const float*)d_in[15];
  const float* cs_be = (const float*)d_in[16];
  const float* cs_m  = (const float*)d_in[17];
  const float* cs_v  = (const float*)d_in[18];
  const float* lin_W = (const float*)d_in[19];
  const float* lin_b = (const float*)d_in[20];
  float* out = (float*)d_out;

  size_t cur = 0;
  auto take = [&](size_t bytes) -> void* {
    void* p = (char*)d_ws + cur;
    cur += (bytes + 255) & ~(size_t)255;
    return p;
  };
  int* cnt  = (int*)take((N_NODES + 1) * sizeof(int));
  size_t zbytes = cur;                       // cnt zeroed every call
  int* goff = (int*)take((N_GRAPHS + 1) * sizeof(int));
  int* csr  = (int*)take((size_t)(N_NODES + 1) * CAP * sizeof(int));
  unsigned short* bufA = (unsigned short*)take((size_t)(N_NODES + 1) * HDIM * sizeof(unsigned short));
  unsigned short* bufB = (unsigned short*)take((size_t)(N_NODES + 1) * HDIM * sizeof(unsigned short));
  (void)ws_size; (void)in_sizes; (void)n_in; (void)out_size;

  hipMemsetAsync(cnt, 0, zbytes, stream);
  hipMemsetAsync(bufA + (size_t)ZNODE * HDIM, 0, HDIM * sizeof(unsigned short), stream);
  hipMemsetAsync(out, 0, N_GRAPHS * 64 * sizeof(float), stream);

  prefill_kernel<<<(N_NODES + 256) / 256, 256, 0, stream>>>(csr);
  fill_kernel<<<RNG * CHUNKS, 256, 0, stream>>>(ei, cnt, csr);
  cvt_pad_kernel<<<2048, 256, 0, stream>>>(x, bufB);   // x -> padded bf16 bufB
  goff_kernel<<<1, 256, 0, stream>>>(batch, goff);

  const int NBLK = (N_NODES + 63) / 64;      // 1563 blocks x 512 thr (8 waves)

  // conv1: bufB(x) -> bufA
  conv_kernel<false><<<NBLK, 512, 0, stream>>>(bufB, bufA, cnt, csr,
      c1_W1, c1_b1, c1_W2, c1_b2, c1_g, c1_be, c1_m, c1_v);

  // 4 residual convs: A->B->A->B->A
  unsigned short* srcp = bufA;
  unsigned short* dstp = bufB;
  for (int l = 0; l < N_RES; ++l) {
    conv_kernel<true><<<NBLK, 512, 0, stream>>>(srcp, dstp, cnt, csr,
        cs_W1 + l * 4096, cs_b1 + l * 64, cs_W2 + l * 4096, cs_b2 + l * 64,
        cs_g + l * 64, cs_be + l * 64, cs_m + l * 64, cs_v + l * 64);
    unsigned short* tmp = srcp; srcp = dstp; dstp = tmp;
  }
  // final h in bufA (srcp); fused head + pool -> out, then divide by counts
  head_pool_kernel<<<NBLK, 512, 0, stream>>>(srcp, out, batch, lin_W, lin_b);
  div_kernel<<<(N_GRAPHS * 64 + 255) / 256, 256, 0, stream>>>(out, goff);
}

// Round 12
// 293.940 us; speedup vs baseline: 3.2484x; 1.5531x over previous
//
#include <hip/hip_runtime.h>
#include <hip/hip_bf16.h>

// GIN forward, MI355X. Sizes fixed by the reference.
constexpr int N_NODES  = 100000;
constexpr int N_EDGES  = 1280000;
constexpr int HDIM     = 64;
constexpr int N_GRAPHS = 128;
constexpr int N_RES    = 4;
constexpr int CAP      = 64;       // CSR slots per node (P(deg>64) ~ e-60)
constexpr int ZNODE    = N_NODES;  // zero pad row index in padded h buffers

typedef __attribute__((ext_vector_type(8))) short bf16x8;
typedef __attribute__((ext_vector_type(4))) float f32x4;

// ---- bf16 helpers (RNE) ----
__device__ __forceinline__ unsigned f2bf1(float f) {
  unsigned u = __float_as_uint(f);
  return (u + 0x7fffu + ((u >> 16) & 1u)) >> 16;
}
__device__ __forceinline__ unsigned packbf(float lo, float hi) {
  return f2bf1(lo) | (f2bf1(hi) << 16);
}
__device__ __forceinline__ float bflo(unsigned u) { return __uint_as_float(u << 16); }
__device__ __forceinline__ float bfhi(unsigned u) { return __uint_as_float(u & 0xffff0000u); }
__device__ __forceinline__ float bf2f(unsigned short h) { return __uint_as_float(((unsigned)h) << 16); }

__device__ __forceinline__ float tanh_fast(float x) {
  float xc = fminf(fmaxf(x, -15.f), 15.f);
  float e = __expf(2.f * xc);
  return __fdividef(e - 1.f, e + 1.f);
}

// ---------------- CSR build: XCD-binned single pass ----------------
constexpr int RNG = 8;
constexpr int RSZ = N_NODES / RNG;      // 12500
constexpr int CHUNKS = 128;
constexpr int CSZ = N_EDGES / CHUNKS;   // 10000

__global__ void fill_kernel(const int* __restrict__ ei,
                            int* __restrict__ cnt, int* __restrict__ csr) {
  int b = blockIdx.x;
  int lo = (b & (RNG - 1)) * RSZ;
  int hi = lo + RSZ;
  int base = (b >> 3) * CSZ;
  for (int i = base + threadIdx.x * 4; i < base + CSZ; i += 256 * 4) {
    int4 d4 = *(const int4*)&ei[N_EDGES + i];
    int4 s4 = *(const int4*)&ei[i];
    if (d4.x >= lo && d4.x < hi) { int p = atomicAdd(&cnt[d4.x], 1); csr[d4.x * CAP + (p & (CAP - 1))] = s4.x; }
    if (d4.y >= lo && d4.y < hi) { int p = atomicAdd(&cnt[d4.y], 1); csr[d4.y * CAP + (p & (CAP - 1))] = s4.y; }
    if (d4.z >= lo && d4.z < hi) { int p = atomicAdd(&cnt[d4.z], 1); csr[d4.z * CAP + (p & (CAP - 1))] = s4.z; }
    if (d4.w >= lo && d4.w < hi) { int p = atomicAdd(&cnt[d4.w], 1); csr[d4.w * CAP + (p & (CAP - 1))] = s4.w; }
  }
}

// pre-write ZNODE sentinel into slots 0..15 of every row (runs BEFORE fill)
__global__ void prefill_kernel(int* __restrict__ csr) {
  int n = blockIdx.x * blockDim.x + threadIdx.x;
  if (n > N_NODES) return;
  int4 z4 = make_int4(ZNODE, ZNODE, ZNODE, ZNODE);
  int4* p = (int4*)(csr + (size_t)n * CAP);
  p[0] = z4; p[1] = z4; p[2] = z4; p[3] = z4;
}

// x (f32) -> padded bf16 buffer; pad row zero
__global__ void cvt_pad_kernel(const float* __restrict__ x, unsigned short* __restrict__ dst) {
  constexpr int TOT = (N_NODES + 1) * HDIM / 2;   // uint (bf16x2) count
  constexpr int XN  = N_NODES * HDIM / 2;
  unsigned* d = (unsigned*)dst;
  for (int i = blockIdx.x * blockDim.x + threadIdx.x; i < TOT; i += gridDim.x * blockDim.x) {
    unsigned v = 0;
    if (i < XN) { float2 f = *(const float2*)&x[i * 2]; v = packbf(f.x, f.y); }
    d[i] = v;
  }
}

// goff[g] = lower_bound(batch, g) over sorted batch ids
__global__ void goff_kernel(const int* __restrict__ batch, int* __restrict__ goff) {
  int g = threadIdx.x;
  if (g > N_GRAPHS) return;
  int lo = 0, hi = N_NODES;
  while (lo < hi) {
    int mid = (lo + hi) >> 1;
    if (batch[mid] < g) lo = mid + 1; else hi = mid;
  }
  goff[g] = lo;
}

// ---------------- pack all 10 conv weight matrices into MFMA B-fragments ----
// dst per matrix (mat = layer*2 + isW2): 8192 bf16 = hi[4096] | lo[4096].
// element e = f*512 + lane*8 + i maps to W[ks*32 + (lane>>4)*8 + i][tc*16 + (lane&15)],
// f = tc*2 + ks. Same (lane,elem)->k map is used for the A fragments, so the
// contraction is correct regardless of the hardware's internal k-slot order.
// Layer l block: W1 at l*16384, W2 at l*16384 + 8192.
__global__ void packw_kernel(const float* __restrict__ c1W1, const float* __restrict__ c1W2,
                             const float* __restrict__ csW1, const float* __restrict__ csW2,
                             unsigned short* __restrict__ dst) {
  int idx = blockIdx.x * 256 + threadIdx.x;   // 10 * 4096
  if (idx >= 10 * 4096) return;
  int mat = idx >> 12;
  int e   = idx & 4095;
  int f    = e >> 9;
  int lane = (e >> 3) & 63;
  int i    = e & 7;
  int tc = f >> 1, ks = f & 1;
  int krow = ks * 32 + (lane >> 4) * 8 + i;
  int col  = tc * 16 + (lane & 15);
  int l = mat >> 1;
  const float* W;
  if (l == 0) W = (mat & 1) ? c1W2 : c1W1;
  else        W = ((mat & 1) ? csW2 : csW1) + (size_t)(l - 1) * 4096;
  float w = W[krow * 64 + col];
  unsigned short hi = (unsigned short)f2bf1(w);
  unsigned short lo = (unsigned short)f2bf1(w - bf2f(hi));
  unsigned short* d = dst + (size_t)mat * 8192;
  d[e] = hi;
  d[4096 + e] = lo;
}

// ---------------- fused GIN conv: 256 thr = 4 waves, 64 nodes, MFMA MLP -----
// Gather (R8-proven) -> z split to bf16 hi/lo in LDS [node][k] stride 72.
// MLP: per wave, its 16 nodes x 64 feats via mfma_f32_16x16x32_bf16,
// 3-product split (zh*Wh + zl*Wh + zh*Wl), W pre-packed in B-frag order.
// __syncthreads() after each LDS produce phase = compiler fence (rule #18
// class) + hw sync; rows are wave-private so it's cheap insurance.
template <bool RESID>
__global__ __launch_bounds__(256, 6)
void conv_kernel(const unsigned short* __restrict__ hin, unsigned short* __restrict__ hout,
                 const int* __restrict__ cnt, const int* __restrict__ csr,
                 const unsigned short* __restrict__ Wpk,   // layer block: W1 hi|lo, then W2 hi|lo
                 const float* __restrict__ b1, const float* __restrict__ b2,
                 const float* __restrict__ gam, const float* __restrict__ bet,
                 const float* __restrict__ rm, const float* __restrict__ rv) {
  __shared__ __align__(16) unsigned short zb0[64][72];   // hi
  __shared__ __align__(16) unsigned short zb1[64][72];   // lo
  const int t   = threadIdx.x;
  const int ln  = t & 63;
  const int wid = __builtin_amdgcn_readfirstlane(t >> 6);   // 0..3
  const int lc  = ln & 31;
  const bool hiH = ln >= 32;
  const int nb  = blockIdx.x * 64;
  const unsigned* hb = (const unsigned*)hin;   // row stride 32 words

  // ---- gather: wave wid -> local nodes [16*wid, 16*wid+16), 8 pairs ----
  for (int p = 0; p < 8; ++p) {
    int m = wid * 16 + 2 * p;
    int nA = nb + m; if (nA > ZNODE) nA = ZNODE;
    int nB = nA + 1; if (nB > ZNODE) nB = ZNODE;
    const int* rA = csr + (size_t)nA * CAP;
    const int* rB = csr + (size_t)nB * CAP;
    int4 a0 = *(const int4*)(rA + 0), a1q = *(const int4*)(rA + 4);
    int4 a2 = *(const int4*)(rA + 8), a3q = *(const int4*)(rA + 12);
    int4 b0 = *(const int4*)(rB + 0), b1q = *(const int4*)(rB + 4);
    int4 b2q = *(const int4*)(rB + 8), b3q = *(const int4*)(rB + 12);
    int dA = cnt[nA], dB = cnt[nB];

    int self = hiH ? nB : nA;
    float z0, z1;
    { unsigned u = hb[(size_t)self * 32 + lc]; z0 = bflo(u); z1 = bfhi(u); }
    int i0  = hiH ? b0.x  : a0.x;   int i1  = hiH ? b0.y  : a0.y;
    int i2  = hiH ? b0.z  : a0.z;   int i3  = hiH ? b0.w  : a0.w;
    int i4  = hiH ? b1q.x : a1q.x;  int i5  = hiH ? b1q.y : a1q.y;
    int i6  = hiH ? b1q.z : a1q.z;  int i7  = hiH ? b1q.w : a1q.w;
    int i8  = hiH ? b2q.x : a2.x;   int i9  = hiH ? b2q.y : a2.y;
    int i10 = hiH ? b2q.z : a2.z;   int i11 = hiH ? b2q.w : a2.w;
    int i12 = hiH ? b3q.x : a3q.x;  int i13 = hiH ? b3q.y : a3q.y;
    int i14 = hiH ? b3q.z : a3q.z;  int i15 = hiH ? b3q.w : a3q.w;
#define GACC(ix) { unsigned u = hb[(size_t)(ix) * 32 + lc]; z0 += bflo(u); z1 += bfhi(u); }
    GACC(i0)  GACC(i1)  GACC(i2)  GACC(i3)
    GACC(i4)  GACC(i5)  GACC(i6)  GACC(i7)
    GACC(i8)  GACC(i9)  GACC(i10) GACC(i11)
    GACC(i12) GACC(i13) GACC(i14) GACC(i15)
#undef GACC
    if (dA > 16 && !hiH)
      for (int q = 16; q < dA; ++q) { unsigned u = hb[(size_t)rA[q] * 32 + lc]; z0 += bflo(u); z1 += bfhi(u); }
    if (dB > 16 && hiH)
      for (int q = 16; q < dB; ++q) { unsigned u = hb[(size_t)rB[q] * 32 + lc]; z0 += bflo(u); z1 += bfhi(u); }
    int mr = m + (hiH ? 1 : 0);
    // split hi/lo; features 2lc, 2lc+1 -> one b32 write per buffer
    unsigned h0 = f2bf1(z0);
    float r0 = z0 - __uint_as_float(h0 << 16);
    float r1 = z1 - __uint_as_float(f2bf1(z1) << 16);
    *(unsigned*)&zb0[mr][2 * lc] = h0 | (f2bf1(z1) << 16);
    *(unsigned*)&zb1[mr][2 * lc] = f2bf1(r0) | (f2bf1(r1) << 16);
  }
  __syncthreads();    // fence: order gather LDS stores before b128 frag reads

  const int l15 = ln & 15, lg = ln >> 4;
  const int arow = 16 * wid + l15;                  // A-frag row (node-local)
  const unsigned short* W1pk = Wpk;
  const unsigned short* W2pk = Wpk + 8192;          // FIX: per-matrix block is 8192 bf16

  // ---- matvec 1: a1 = relu(z @ W1 + b1), wave-local 16 nodes x 64 feats ----
  f32x4 acc[4];
#pragma unroll
  for (int tc = 0; tc < 4; ++tc) {
    float bv = b1[tc * 16 + l15];
    acc[tc] = (f32x4){bv, bv, bv, bv};
  }
#pragma unroll
  for (int ks = 0; ks < 2; ++ks) {
    bf16x8 ah = *(const bf16x8*)&zb0[arow][lg * 8 + ks * 32];
    bf16x8 al = *(const bf16x8*)&zb1[arow][lg * 8 + ks * 32];
#pragma unroll
    for (int tc = 0; tc < 4; ++tc) {
      bf16x8 bh = *(const bf16x8*)&W1pk[(size_t)((tc * 2 + ks) * 64 + ln) * 8];
      bf16x8 bl = *(const bf16x8*)&W1pk[4096 + (size_t)((tc * 2 + ks) * 64 + ln) * 8];
      acc[tc] = __builtin_amdgcn_mfma_f32_16x16x32_bf16(ah, bh, acc[tc], 0, 0, 0);
      acc[tc] = __builtin_amdgcn_mfma_f32_16x16x32_bf16(al, bh, acc[tc], 0, 0, 0);
      acc[tc] = __builtin_amdgcn_mfma_f32_16x16x32_bf16(ah, bl, acc[tc], 0, 0, 0);
    }
  }
  __syncthreads();    // all matvec-1 A reads complete before a1 overwrite

  // ---- ReLU + split + write a1 back to zb (same wave-private rows) ----
#pragma unroll
  for (int tc = 0; tc < 4; ++tc) {
#pragma unroll
    for (int r = 0; r < 4; ++r) {
      float v = fmaxf(acc[tc][r], 0.0f);
      int node = 16 * wid + lg * 4 + r;
      int feat = tc * 16 + l15;
      unsigned short hh = (unsigned short)f2bf1(v);
      zb0[node][feat] = hh;
      zb1[node][feat] = (unsigned short)f2bf1(v - bf2f(hh));
    }
  }
  __syncthreads();    // fence: order a1 stores before matvec-2 frag reads

  // ---- matvec 2: y = a1 @ W2 + b2 ----
#pragma unroll
  for (int tc = 0; tc < 4; ++tc) {
    float bv = b2[tc * 16 + l15];
    acc[tc] = (f32x4){bv, bv, bv, bv};
  }
#pragma unroll
  for (int ks = 0; ks < 2; ++ks) {
    bf16x8 ah = *(const bf16x8*)&zb0[arow][lg * 8 + ks * 32];
    bf16x8 al = *(const bf16x8*)&zb1[arow][lg * 8 + ks * 32];
#pragma unroll
    for (int tc = 0; tc < 4; ++tc) {
      bf16x8 bh = *(const bf16x8*)&W2pk[(size_t)((tc * 2 + ks) * 64 + ln) * 8];
      bf16x8 bl = *(const bf16x8*)&W2pk[4096 + (size_t)((tc * 2 + ks) * 64 + ln) * 8];
      acc[tc] = __builtin_amdgcn_mfma_f32_16x16x32_bf16(ah, bh, acc[tc], 0, 0, 0);
      acc[tc] = __builtin_amdgcn_mfma_f32_16x16x32_bf16(al, bh, acc[tc], 0, 0, 0);
      acc[tc] = __builtin_amdgcn_mfma_f32_16x16x32_bf16(ah, bl, acc[tc], 0, 0, 0);
    }
  }

  // ---- ReLU + BN (+residual) + bf16 store ----
#pragma unroll
  for (int tc = 0; tc < 4; ++tc) {
    int feat = tc * 16 + l15;
    float sc = gam[feat] * rsqrtf(rv[feat] + 1e-5f);
    float sh = bet[feat] - rm[feat] * sc;
#pragma unroll
    for (int r = 0; r < 4; ++r) {
      int gn = nb + 16 * wid + lg * 4 + r;
      bool v = gn < N_NODES;
      int gnc = v ? gn : ZNODE;
      float y = fmaxf(acc[tc][r], 0.0f) * sc + sh;
      if (RESID) y += bf2f(hin[(size_t)gnc * 64 + feat]);
      if (v) hout[(size_t)gn * 64 + feat] = (unsigned short)f2bf1(y);
    }
  }
}

// ---------------- fused head + mean-pool partial sums (R9-proven) ----------
__global__ __launch_bounds__(512, 6)
void head_pool_kernel(const unsigned short* __restrict__ hin, float* __restrict__ out,
                      const int* __restrict__ batch,
                      const float* __restrict__ W, const float* __restrict__ b) {
  const int t   = threadIdx.x;
  const int ln  = t & 63;
  const int wid = __builtin_amdgcn_readfirstlane(t >> 6);
  const int n = blockIdx.x * 64 + ln;
  const bool valid = n < N_NODES;
  const int nn = valid ? n : ZNODE;
  const unsigned* hb = (const unsigned*)hin;

  unsigned zp[32];
#pragma unroll
  for (int cc = 0; cc < 8; ++cc) {
    uint4 u = *(const uint4*)&hb[(size_t)nn * 32 + cc * 4];
    zp[cc * 4 + 0] = u.x; zp[cc * 4 + 1] = u.y;
    zp[cc * 4 + 2] = u.z; zp[cc * 4 + 3] = u.w;
  }

  const float* Wp = W + wid * 8;
  const float* bp = b + wid * 8;
  float acc[8];
#pragma unroll
  for (int f = 0; f < 8; ++f) acc[f] = bp[f];
#pragma unroll
  for (int w = 0; w < 32; ++w) {
    float zlo = bflo(zp[w]), zhi = bfhi(zp[w]);
#pragma unroll
    for (int f = 0; f < 8; ++f) acc[f] = fmaf(zlo, Wp[(2 * w) * 64 + f], acc[f]);
#pragma unroll
    for (int f = 0; f < 8; ++f) acc[f] = fmaf(zhi, Wp[(2 * w + 1) * 64 + f], acc[f]);
  }
#pragma unroll
  for (int f = 0; f < 8; ++f) acc[f] = tanh_fast(acc[f]);

  int bg = valid ? batch[n] : -1;
  int gmax = bg;
#pragma unroll
  for (int off = 32; off >= 1; off >>= 1) gmax = max(gmax, __shfl_xor(gmax, off));
  gmax = __builtin_amdgcn_readfirstlane(gmax);
  int g0 = __builtin_amdgcn_readfirstlane(bg);

  for (int g = g0; g <= gmax; ++g) {
    float s[8];
    bool inG = (bg == g);
#pragma unroll
    for (int f = 0; f < 8; ++f) s[f] = inG ? acc[f] : 0.0f;
#pragma unroll
    for (int off = 1; off <= 32; off <<= 1) {
#pragma unroll
      for (int f = 0; f < 8; ++f) s[f] += __shfl_xor(s[f], off);
    }
    float sv = s[0];
    sv = (ln == 1) ? s[1] : sv;  sv = (ln == 2) ? s[2] : sv;
    sv = (ln == 3) ? s[3] : sv;  sv = (ln == 4) ? s[4] : sv;
    sv = (ln == 5) ? s[5] : sv;  sv = (ln == 6) ? s[6] : sv;
    sv = (ln == 7) ? s[7] : sv;
    if (ln < 8) atomicAdd(&out[g * 64 + wid * 8 + ln], sv);
  }
}

// out[g][f] /= max(count_g, 1)
__global__ void div_kernel(float* __restrict__ out, const int* __restrict__ goff) {
  int i = blockIdx.x * blockDim.x + threadIdx.x;
  if (i >= N_GRAPHS * 64) return;
  int g = i >> 6;
  int c = goff[g + 1] - goff[g];
  out[i] /= (float)max(c, 1);
}

// ---------------- launch ----------------
extern "C" void kernel_launch(void* const* d_in, const int* in_sizes, int n_in,
                              void* d_out, int out_size, void* d_ws, size_t ws_size,
                              hipStream_t stream) {
  const float* x     = (const float*)d_in[0];
  const int*   ei    = (const int*)d_in[1];
  const int*   batch = (const int*)d_in[2];
  const float* c1_W1 = (const float*)d_in[3];
  const float* c1_b1 = (const float*)d_in[4];
  const float* c1_W2 = (const float*)d_in[5];
  const float* c1_b2 = (const float*)d_in[6];
  const float* c1_g  = (const float*)d_in[7];
  const float* c1_be = (const float*)d_in[8];
  const float* c1_m  = (const float*)d_in[9];
  const float* c1_v  = (const float*)d_in[10];
  const float* cs_W1 = (const float*)d_in[11];
  const float* cs_b1 = (const float*)d_in[12];
  const float* cs_W2 = (const float*)d_in[13];
  const float* cs_b2 = (const float*)d_in[14];
  const float* cs_g  = (const float*)d_in[15];
  const float* cs_be = (const float*)d_in[16];
  const float* cs_m  = (const float*)d_in[17];
  const float* cs_v  = (const float*)d_in[18];
  const float* lin_W = (const float*)d_in[19];
  const float* lin_b = (const float*)d_in[20];
  float* out = (float*)d_out;

  size_t cur = 0;
  auto take = [&](size_t bytes) -> void* {
    void* p = (char*)d_ws + cur;
    cur += (bytes + 255) & ~(size_t)255;
    return p;
  };
  int* cnt  = (int*)take((N_NODES + 1) * sizeof(int));
  size_t zbytes = cur;                       // cnt zeroed every call
  int* goff = (int*)take((N_GRAPHS + 1) * sizeof(int));
  int* csr  = (int*)take((size_t)(N_NODES + 1) * CAP * sizeof(int));
  unsigned short* bufA = (unsigned short*)take((size_t)(N_NODES + 1) * HDIM * sizeof(unsigned short));
  unsigned short* bufB = (unsigned short*)take((size_t)(N_NODES + 1) * HDIM * sizeof(unsigned short));
  unsigned short* wpk  = (unsigned short*)take((size_t)10 * 8192 * sizeof(unsigned short));
  (void)ws_size; (void)in_sizes; (void)n_in; (void)out_size;

  hipMemsetAsync(cnt, 0, zbytes, stream);
  hipMemsetAsync(bufA + (size_t)ZNODE * HDIM, 0, HDIM * sizeof(unsigned short), stream);
  hipMemsetAsync(out, 0, N_GRAPHS * 64 * sizeof(float), stream);

  prefill_kernel<<<(N_NODES + 256) / 256, 256, 0, stream>>>(csr);
  fill_kernel<<<RNG * CHUNKS, 256, 0, stream>>>(ei, cnt, csr);
  cvt_pad_kernel<<<2048, 256, 0, stream>>>(x, bufB);   // x -> padded bf16 bufB
  goff_kernel<<<1, 256, 0, stream>>>(batch, goff);
  packw_kernel<<<160, 256, 0, stream>>>(c1_W1, c1_W2, cs_W1, cs_W2, wpk);

  const int NBLK = (N_NODES + 63) / 64;      // 1563 blocks x 256 thr (4 waves)

  // conv1: bufB(x) -> bufA  (layer l weight block at wpk + l*16384)
  conv_kernel<false><<<NBLK, 256, 0, stream>>>(bufB, bufA, cnt, csr,
      wpk, c1_b1, c1_b2, c1_g, c1_be, c1_m, c1_v);

  // 4 residual convs: A->B->A->B->A
  unsigned short* srcp = bufA;
  unsigned short* dstp = bufB;
  for (int l = 0; l < N_RES; ++l) {
    conv_kernel<true><<<NBLK, 256, 0, stream>>>(srcp, dstp, cnt, csr,
        wpk + (size_t)(l + 1) * 16384,
        cs_b1 + l * 64, cs_b2 + l * 64,
        cs_g + l * 64, cs_be + l * 64, cs_m + l * 64, cs_v + l * 64);
    unsigned short* tmp = srcp; srcp = dstp; dstp = tmp;
  }
  // final h in bufA (srcp); fused head + pool -> out, then divide by counts
  head_pool_kernel<<<NBLK, 512, 0, stream>>>(srcp, out, batch, lin_W, lin_b);
  div_kernel<<<(N_GRAPHS * 64 + 255) / 256, 256, 0, stream>>>(out, goff);
}